// Round 5
// baseline (717.564 us; speedup 1.0000x reference)
//
#include <hip/hip_runtime.h>
#include <cmath>

#define HW   256
#define NPIX 65536       // 256*256
#define NP   65600       // padded channel stride for yr (64-entry zero pad)
#define CIN  64
#define C2   340
#define HID  170

typedef _Float16 f16x8 __attribute__((ext_vector_type(8)));
typedef float    f32x4 __attribute__((ext_vector_type(4)));

// Orthonormal DCT-II basis for n=8 as compile-time constants.
#define A0 0.35355339059327373f
#define A1 0.49039264020161522f
#define A2 0.46193976625564337f
#define A3 0.41573480615127262f
#define A4 0.35355339059327379f
#define A5 0.27778511650980114f
#define A6 0.19134171618254492f
#define A7 0.09754516100806417f

__device__ static constexpr float MD[8][8] = {
    { A0,  A0,  A0,  A0,  A0,  A0,  A0,  A0},
    { A1,  A3,  A5,  A7, -A7, -A5, -A3, -A1},
    { A2,  A6, -A6, -A2, -A2, -A6,  A6,  A2},
    { A3, -A7, -A1, -A5,  A5,  A1,  A7, -A3},
    { A4, -A4, -A4,  A4,  A4, -A4, -A4,  A4},
    { A5, -A1,  A7,  A3, -A3, -A7,  A1, -A5},
    { A6, -A2,  A2, -A6, -A6,  A2, -A2,  A6},
    { A7, -A5,  A3, -A1,  A1, -A3,  A5, -A7},
};

// Rotated Csh column: logical (block,within) at row, channel ocl ->
// physical column. Breaks the 8-way same-bank pattern of straight layout.
__device__ __forceinline__ int pcolrot(int blk, int row, int ocl) {
    return ((blk + row + (ocl >> 2)) & 3) << 3;
}

// ---------------------------------------------------------------------------
// Prep: WinH fp16 [352][64] (rows >=340 zero), WoutKH fp16 [64][192]
// (WoutKH[o][h] = Wout[o][h], h>=170 zero).
// ---------------------------------------------------------------------------
__global__ __launch_bounds__(256) void kprep(const float* __restrict__ Win,
                                             const float* __restrict__ Wout,
                                             _Float16* __restrict__ WinH,
                                             _Float16* __restrict__ WoutKH)
{
    const int i = blockIdx.x * 256 + threadIdx.x;
    if (i < 352 * 64) WinH[i] = (i < C2 * 64) ? (_Float16)Win[i] : (_Float16)0.f;
    if (i < 64 * 192) {
        const int o = i / 192, h = i - o * 192;
        WoutKH[i] = (h < HID) ? (_Float16)Wout[o * HID + h] : (_Float16)0.f;
    }
}

// ---------------------------------------------------------------------------
// Kernel A: project_in via MFMA + VALU DCT/quant/IDCT -> yr fp16 (padded NP).
// Block 256 (4 waves), tile 32x8 px (4 patches wide, so each (oc,row) global
// write is 4 x 16B = 64B full-sector).  11 chunks of 32 oc.
// ---------------------------------------------------------------------------
__global__ __launch_bounds__(256) void kA(
    const float* __restrict__ x,        // [nb][64][256][256]
    const _Float16* __restrict__ WinH,  // [352][64] fp16 (zero-padded)
    const float* __restrict__ quant,    // [340][8][8]
    _Float16* __restrict__ yr)          // [nb][340][NP] fp16
{
    const int tid  = threadIdx.x;
    const int tile = blockIdx.x;
    const int bb   = blockIdx.y;
    const int ty = tile >> 3, tx = tile & 7;     // ty 0..31, tx 0..7
    const int y0 = ty * 8,    x0 = tx * 32;
    const int r  = tid >> 5,  c  = tid & 31;     // pixel within 8x32 tile
    const int wv = tid >> 6;
    const int l15 = tid & 15, quad = (tid & 63) >> 4;

    __shared__ union {
        _Float16 ash[256 * 64];         // 32768 B (prologue only)
        float    csh[32 * 264];         // 33792 B (chunk loop)
    } shm;

    // Zero yr's per-channel pad region for this batch (tile 0 blocks only).
    if (tile == 0) {
        const f16x8 z = {(_Float16)0.f,(_Float16)0.f,(_Float16)0.f,(_Float16)0.f,
                         (_Float16)0.f,(_Float16)0.f,(_Float16)0.f,(_Float16)0.f};
#pragma unroll 1
        for (int it = 0; it < 11; ++it) {
            const int idx = tid + it * 256;            // 2720 groups of 8
            if (idx < C2 * 8) {
                const int oc = idx >> 3, sub = idx & 7;
                *(f16x8*)&yr[(size_t)(bb * C2 + oc) * NP + NPIX + sub * 8] = z;
            }
        }
    }

    // ---- Stage x tile -> LDS fp16 (XOR swizzle on 8-elt units) ----
    const float* xp = x + (size_t)bb * (CIN * NPIX) + (y0 + r) * HW + (x0 + c);
    const int sw = tid & 7;
#pragma unroll
    for (int u = 0; u < 8; ++u) {
        union { _Float16 h[8]; f16x8 v; } pk;
#pragma unroll
        for (int j = 0; j < 8; ++j) pk.h[j] = (_Float16)xp[(size_t)(u * 8 + j) * NPIX];
        *(f16x8*)&shm.ash[tid * 64 + ((u ^ sw) * 8)] = pk.v;
    }
    __syncthreads();

    // ---- Hoist A fragments into registers (reused by every chunk) ----
    f16x8 af0[4], af1[4];
#pragma unroll
    for (int tt = 0; tt < 4; ++tt) {
        const int apx = (wv * 4 + tt) * 16 + l15;
        const int asw = apx & 7;
        af0[tt] = *(const f16x8*)&shm.ash[apx * 64 + ((quad ^ asw) * 8)];
        af1[tt] = *(const f16x8*)&shm.ash[apx * 64 + (((4 + quad) ^ asw) * 8)];
    }
    __syncthreads();   // Ash dead; csh may now be written

    // DCT roles: patch = 8 rows x 8 cols at (rows 0..7, cols pat*8..pat*8+7)
    const int ch  = tid >> 5;             // 0..7 (channel-of-32 sub-block base)
    const int pat = (tid >> 3) & 3;       // 0..3 (horizontal patch)
    const int lan = tid & 7;              // 0..7

#pragma unroll 1
    for (int sc = 0; sc < 11; ++sc) {
        const int oc0 = sc * 32;

        // ---- MFMA projection: 32 oc (2 groups of 16) ----
#pragma unroll
        for (int g2 = 0; g2 < 2; ++g2) {
            const int ocb = oc0 + g2 * 16 + l15;           // WinH zero-padded
            const f16x8 b0 = *(const f16x8*)(WinH + ocb * 64 + quad * 8);
            const f16x8 b1 = *(const f16x8*)(WinH + ocb * 64 + 32 + quad * 8);
#pragma unroll
            for (int tt = 0; tt < 4; ++tt) {
                const int tile16 = wv * 4 + tt;
                f32x4 acc = {0.f, 0.f, 0.f, 0.f};
                acc = __builtin_amdgcn_mfma_f32_16x16x32_f16(af0[tt], b0, acc, 0, 0, 0);
                acc = __builtin_amdgcn_mfma_f32_16x16x32_f16(af1[tt], b1, acc, 0, 0, 0);
                // D: col=l15 (oc), row=quad*4+reg (px). px = tile16*16+quad*4:
                // tile row = tile16>>1, block = (tile16&1)*2 + (quad>>1)
                const int ocl = g2 * 16 + l15;
                const int prow = tile16 >> 1;
                const int blk  = ((tile16 & 1) << 1) | (quad >> 1);
                *(f32x4*)&shm.csh[ocl * 264 + prow * 32 + pcolrot(blk, prow, ocl)
                                  + (quad & 1) * 4] = acc;
            }
        }
        __syncthreads();

        // ---- R1 (rows): out[j] = sum_q v[q]*MD[j][q], in place, b128 IO ----
#pragma unroll
        for (int di = 0; di < 4; ++di) {
            const int ocl = ch + 8 * di;
            float* row = &shm.csh[ocl * 264 + lan * 32 + pcolrot(pat, lan, ocl)];
            float v[8], o[8];
            *(f32x4*)&v[0] = *(const f32x4*)row;
            *(f32x4*)&v[4] = *(const f32x4*)(row + 4);
#pragma unroll
            for (int j = 0; j < 8; ++j) {
                float s = v[0] * MD[j][0];
#pragma unroll
                for (int q = 1; q < 8; ++q) s = fmaf(v[q], MD[j][q], s);
                o[j] = s;
            }
            *(f32x4*)row       = *(const f32x4*)&o[0];
            *(f32x4*)(row + 4) = *(const f32x4*)&o[4];
        }
        __syncthreads();

        // ---- Cols: d = M v ; d *= quant ; e = M^T d, in place ----
#pragma unroll
        for (int di = 0; di < 4; ++di) {
            const int ocl = ch + 8 * di;
            float v[8], d[8], e[8];
#pragma unroll
            for (int i = 0; i < 8; ++i)
                v[i] = shm.csh[ocl * 264 + i * 32 + pcolrot(pat, i, ocl) + lan];
            int ocq = oc0 + ocl; if (ocq > C2 - 1) ocq = C2 - 1;
            const float* qp = quant + ocq * 64 + lan;
#pragma unroll
            for (int i = 0; i < 8; ++i) {
                float s = v[0] * MD[i][0];
#pragma unroll
                for (int p = 1; p < 8; ++p) s = fmaf(v[p], MD[i][p], s);
                d[i] = s * qp[i * 8];
            }
#pragma unroll
            for (int p = 0; p < 8; ++p) {
                float s = d[0] * MD[0][p];
#pragma unroll
                for (int i = 1; i < 8; ++i) s = fmaf(d[i], MD[i][p], s);
                e[p] = s;
            }
#pragma unroll
            for (int i = 0; i < 8; ++i)
                shm.csh[ocl * 264 + i * 32 + pcolrot(pat, i, ocl) + lan] = e[i];
        }
        __syncthreads();

        // ---- R2 (rows): out[q] = sum_j v[j]*MD[j][q] -> global fp16 ----
#pragma unroll
        for (int di = 0; di < 4; ++di) {
            const int ocl = ch + 8 * di;
            const int oc  = oc0 + ocl;
            const float* row = &shm.csh[ocl * 264 + lan * 32 + pcolrot(pat, lan, ocl)];
            float v[8];
            *(f32x4*)&v[0] = *(const f32x4*)row;
            *(f32x4*)&v[4] = *(const f32x4*)(row + 4);
            union { _Float16 h[8]; f16x8 f; } u;
#pragma unroll
            for (int q = 0; q < 8; ++q) {
                float s = v[0] * MD[0][q];
#pragma unroll
                for (int j = 1; j < 8; ++j) s = fmaf(v[j], MD[j][q], s);
                u.h[q] = (_Float16)s;
            }
            if (oc < C2) {
                // 4 pats x 16B per (oc,row): full 64B sectors.
                f16x8* dst = (f16x8*)(yr + (size_t)(bb * C2 + oc) * NP
                                      + (y0 + lan) * HW + x0 + pat * 8);
                *dst = u.f;
            }
        }
        __syncthreads();
    }
}

// ---------------------------------------------------------------------------
// Kernel B: depthwise 3x3 + exact gelu gate (VALU) + project_out (MFMA).
// Block 256, tile 64x4 px.  6 chunks of 32 h; g staged fp16 in LDS.
// __launch_bounds__(256,2): 256-reg budget so the g pipeline + MFMA acc
// do NOT spill (round-4 WRITE_SIZE showed ~450MB of scratch traffic).
// ---------------------------------------------------------------------------
__global__ __launch_bounds__(256, 2) void kB(
    const _Float16* __restrict__ yr,      // [nb][340][NP] fp16
    const float* __restrict__ Wdw,        // [340][9]
    const _Float16* __restrict__ WoutKH,  // [64][192] fp16 (zero-padded)
    float* __restrict__ out)              // [nb][64][256][256]
{
    const int tid = threadIdx.x;
    const int bb  = blockIdx.y;
    const int tyb = blockIdx.x >> 2, txb = blockIdx.x & 3;
    const int r = tid >> 6, c = tid & 63;
    const int y0 = tyb * 4 + r, x0 = txb * 64 + c;
    const int wv = tid >> 6;
    const int l15 = tid & 15, quad = (tid & 63) >> 4;

    __shared__ union {
        _Float16 g[256 * 32];    // 16384 B: g tile for one 32-h chunk
        float    t[16 * 257];    // 16448 B: epilogue transpose
    } shm;

    const _Float16* ybase = yr + (size_t)bb * C2 * NP;
    const int base0 = y0 * HW + x0;

    // Precompute 9 tap offsets; OOB taps redirect into the zeroed pad.
    int off[9];
    {
        const int padoff = NPIX + (tid & 63) - base0;
        int k = 0;
#pragma unroll
        for (int dy = -1; dy <= 1; ++dy)
#pragma unroll
            for (int dx = -1; dx <= 1; ++dx, ++k) {
                const int gy = y0 + dy, gx = x0 + dx;
                const bool ok = ((unsigned)gy < (unsigned)HW) && ((unsigned)gx < (unsigned)HW);
                off[k] = ok ? (dy * HW + dx) : padoff;
            }
    }

    f32x4 acc[4][4];   // [px-tile tt][oc-group]
#pragma unroll
    for (int a = 0; a < 4; ++a)
#pragma unroll
        for (int b = 0; b < 4; ++b) acc[a][b] = (f32x4){0.f, 0.f, 0.f, 0.f};

#pragma unroll 1
    for (int chunk = 0; chunk < 6; ++chunk) {
        const int h0 = chunk * 32;

        // ---- g for 32 channels -> LDS fp16 (8 channels per u-step to bound
        //      in-flight loads; unroll 1 keeps register pressure low) ----
#pragma unroll 1
        for (int u = 0; u < 4; ++u) {
            union { _Float16 h[8]; f16x8 v; } pk;
#pragma unroll
            for (int j = 0; j < 8; ++j) {
                const int h = h0 + u * 8 + j;
                float gg = 0.f;
                if (h < HID) {
                    const _Float16* p1 = ybase + (size_t)h * NP + base0;
                    const _Float16* p2 = p1 + (size_t)HID * NP;
                    const float* w1 = Wdw + h * 9;
                    const float* w2 = w1 + HID * 9;
                    float s1 = 0.f, s2 = 0.f;
#pragma unroll
                    for (int k = 0; k < 9; ++k) {
                        s1 = fmaf((float)p1[off[k]], w1[k], s1);
                        s2 = fmaf((float)p2[off[k]], w2[k], s2);
                    }
                    gg = 0.5f * s1 * (1.f + erff(s1 * 0.70710678118654752f)) * s2;
                }
                pk.h[j] = (_Float16)gg;
            }
            *(f16x8*)&shm.g[tid * 32 + ((u ^ (tid & 3)) * 8)] = pk.v;
        }
        __syncthreads();

        // ---- MFMA: acc[px, oc] += g[px, h32] * WoutKH[oc][h32] ----
#pragma unroll
        for (int tt = 0; tt < 4; ++tt) {
            const int apx = (wv * 4 + tt) * 16 + l15;
            const f16x8 a = *(const f16x8*)&shm.g[apx * 32 + ((quad ^ (apx & 3)) * 8)];
#pragma unroll
            for (int p = 0; p < 4; ++p) {
                const f16x8 b = *(const f16x8*)(WoutKH + (p * 16 + l15) * 192 + h0 + quad * 8);
                acc[tt][p] = __builtin_amdgcn_mfma_f32_16x16x32_f16(a, b, acc[tt][p], 0, 0, 0);
            }
        }
        __syncthreads();
    }

    // ---- Epilogue: LDS transpose -> coalesced stores (4 passes of 16 oc) ----
    float* ob = out + (size_t)bb * CIN * NPIX + base0;
#pragma unroll 1
    for (int p = 0; p < 4; ++p) {
#pragma unroll
        for (int tt = 0; tt < 4; ++tt) {
            const int px = (wv * 4 + tt) * 16 + quad * 4;
#pragma unroll
            for (int reg = 0; reg < 4; ++reg)
                shm.t[l15 * 257 + px + reg] = acc[tt][p][reg];
        }
        __syncthreads();
#pragma unroll
        for (int o2 = 0; o2 < 16; ++o2)
            ob[(size_t)(p * 16 + o2) * NPIX] = shm.t[o2 * 257 + tid];
        __syncthreads();
    }
}

extern "C" void kernel_launch(void* const* d_in, const int* in_sizes, int n_in,
                              void* d_out, int out_size, void* d_ws, size_t ws_size,
                              hipStream_t stream)
{
    const float* x     = (const float*)d_in[0];
    const float* Win   = (const float*)d_in[1];
    const float* Wdw   = (const float*)d_in[2];
    const float* quant = (const float*)d_in[3];
    const float* Wout  = (const float*)d_in[4];
    float* out = (float*)d_out;

    // ws: WinH [0,45056) ; WoutKH [45056,69632) ; yr at 69632 (16B aligned).
    _Float16* WinH   = (_Float16*)d_ws;
    _Float16* WoutKH = (_Float16*)((char*)d_ws + 45056);
    _Float16* yrbuf  = (_Float16*)((char*)d_ws + 69632);

    const size_t perBatch = (size_t)C2 * NP * sizeof(_Float16);  // 44.6 MB
    const size_t head = 69632;
    const size_t avail = ws_size > head ? ws_size - head : 0;
    int nb = 1;
    if (avail >= 4 * perBatch)      nb = 4;
    else if (avail >= 2 * perBatch) nb = 2;

    kprep<<<88, 256, 0, stream>>>(Win, Wout, WinH, WoutKH);

    for (int b0 = 0; b0 < 4; b0 += nb) {
        dim3 grid(256, nb);
        kA<<<grid, 256, 0, stream>>>(x + (size_t)b0 * CIN * NPIX, WinH, quant, yrbuf);
        kB<<<grid, 256, 0, stream>>>(yrbuf, Wdw, WoutKH, out + (size_t)b0 * CIN * NPIX);
    }
}

// Round 6
// 459.906 us; speedup vs baseline: 1.5602x; 1.5602x over previous
//
#include <hip/hip_runtime.h>
#include <cmath>

#define HW   256
#define NPIX 65536       // 256*256
#define NP   65600       // padded channel stride for yr (64-entry zero pad)
#define CIN  64
#define C2   340
#define HID  170

typedef _Float16 f16x8 __attribute__((ext_vector_type(8)));
typedef float    f32x4 __attribute__((ext_vector_type(4)));

// Orthonormal DCT-II basis for n=8 as compile-time constants.
#define A0 0.35355339059327373f
#define A1 0.49039264020161522f
#define A2 0.46193976625564337f
#define A3 0.41573480615127262f
#define A4 0.35355339059327379f
#define A5 0.27778511650980114f
#define A6 0.19134171618254492f
#define A7 0.09754516100806417f

__device__ static constexpr float MD[8][8] = {
    { A0,  A0,  A0,  A0,  A0,  A0,  A0,  A0},
    { A1,  A3,  A5,  A7, -A7, -A5, -A3, -A1},
    { A2,  A6, -A6, -A2, -A2, -A6,  A6,  A2},
    { A3, -A7, -A1, -A5,  A5,  A1,  A7, -A3},
    { A4, -A4, -A4,  A4,  A4, -A4, -A4,  A4},
    { A5, -A1,  A7,  A3, -A3, -A7,  A1, -A5},
    { A6, -A2,  A2, -A6, -A6,  A2, -A2,  A6},
    { A7, -A5,  A3, -A1,  A1, -A3,  A5, -A7},
};

// Rotated Csh column: logical (block,within) at row, channel ocl ->
// physical column. Breaks the 8-way same-bank pattern of straight layout.
__device__ __forceinline__ int pcolrot(int blk, int row, int ocl) {
    return ((blk + row + (ocl >> 2)) & 3) << 3;
}

// ---------------------------------------------------------------------------
// Prep: WinH fp16 [352][64] (rows >=340 zero), WoutKH fp16 [64][192]
// (WoutKH[o][h] = Wout[o][h], h>=170 zero).
// ---------------------------------------------------------------------------
__global__ __launch_bounds__(256) void kprep(const float* __restrict__ Win,
                                             const float* __restrict__ Wout,
                                             _Float16* __restrict__ WinH,
                                             _Float16* __restrict__ WoutKH)
{
    const int i = blockIdx.x * 256 + threadIdx.x;
    if (i < 352 * 64) WinH[i] = (i < C2 * 64) ? (_Float16)Win[i] : (_Float16)0.f;
    if (i < 64 * 192) {
        const int o = i / 192, h = i - o * 192;
        WoutKH[i] = (h < HID) ? (_Float16)Wout[o * HID + h] : (_Float16)0.f;
    }
}

// ---------------------------------------------------------------------------
// Kernel A: project_in via MFMA + VALU DCT/quant/IDCT -> yr fp16 (padded NP).
// Block 256 (4 waves), tile 32x8 px.  11 chunks of 32 oc.  (unchanged r5)
// ---------------------------------------------------------------------------
__global__ __launch_bounds__(256) void kA(
    const float* __restrict__ x,        // [nb][64][256][256]
    const _Float16* __restrict__ WinH,  // [352][64] fp16 (zero-padded)
    const float* __restrict__ quant,    // [340][8][8]
    _Float16* __restrict__ yr)          // [nb][340][NP] fp16
{
    const int tid  = threadIdx.x;
    const int tile = blockIdx.x;
    const int bb   = blockIdx.y;
    const int ty = tile >> 3, tx = tile & 7;     // ty 0..31, tx 0..7
    const int y0 = ty * 8,    x0 = tx * 32;
    const int r  = tid >> 5,  c  = tid & 31;     // pixel within 8x32 tile
    const int wv = tid >> 6;
    const int l15 = tid & 15, quad = (tid & 63) >> 4;

    __shared__ union {
        _Float16 ash[256 * 64];         // 32768 B (prologue only)
        float    csh[32 * 264];         // 33792 B (chunk loop)
    } shm;

    // Zero yr's per-channel pad region for this batch (tile 0 blocks only).
    if (tile == 0) {
        const f16x8 z = {(_Float16)0.f,(_Float16)0.f,(_Float16)0.f,(_Float16)0.f,
                         (_Float16)0.f,(_Float16)0.f,(_Float16)0.f,(_Float16)0.f};
#pragma unroll 1
        for (int it = 0; it < 11; ++it) {
            const int idx = tid + it * 256;            // 2720 groups of 8
            if (idx < C2 * 8) {
                const int oc = idx >> 3, sub = idx & 7;
                *(f16x8*)&yr[(size_t)(bb * C2 + oc) * NP + NPIX + sub * 8] = z;
            }
        }
    }

    // ---- Stage x tile -> LDS fp16 (XOR swizzle on 8-elt units) ----
    const float* xp = x + (size_t)bb * (CIN * NPIX) + (y0 + r) * HW + (x0 + c);
    const int sw = tid & 7;
#pragma unroll
    for (int u = 0; u < 8; ++u) {
        union { _Float16 h[8]; f16x8 v; } pk;
#pragma unroll
        for (int j = 0; j < 8; ++j) pk.h[j] = (_Float16)xp[(size_t)(u * 8 + j) * NPIX];
        *(f16x8*)&shm.ash[tid * 64 + ((u ^ sw) * 8)] = pk.v;
    }
    __syncthreads();

    // ---- Hoist A fragments into registers (reused by every chunk) ----
    f16x8 af0[4], af1[4];
#pragma unroll
    for (int tt = 0; tt < 4; ++tt) {
        const int apx = (wv * 4 + tt) * 16 + l15;
        const int asw = apx & 7;
        af0[tt] = *(const f16x8*)&shm.ash[apx * 64 + ((quad ^ asw) * 8)];
        af1[tt] = *(const f16x8*)&shm.ash[apx * 64 + (((4 + quad) ^ asw) * 8)];
    }
    __syncthreads();   // Ash dead; csh may now be written

    // DCT roles
    const int ch  = tid >> 5;             // 0..7
    const int pat = (tid >> 3) & 3;       // 0..3 (horizontal patch)
    const int lan = tid & 7;              // 0..7

#pragma unroll 1
    for (int sc = 0; sc < 11; ++sc) {
        const int oc0 = sc * 32;

        // ---- MFMA projection: 32 oc (2 groups of 16) ----
#pragma unroll
        for (int g2 = 0; g2 < 2; ++g2) {
            const int ocb = oc0 + g2 * 16 + l15;           // WinH zero-padded
            const f16x8 b0 = *(const f16x8*)(WinH + ocb * 64 + quad * 8);
            const f16x8 b1 = *(const f16x8*)(WinH + ocb * 64 + 32 + quad * 8);
#pragma unroll
            for (int tt = 0; tt < 4; ++tt) {
                const int tile16 = wv * 4 + tt;
                f32x4 acc = {0.f, 0.f, 0.f, 0.f};
                acc = __builtin_amdgcn_mfma_f32_16x16x32_f16(af0[tt], b0, acc, 0, 0, 0);
                acc = __builtin_amdgcn_mfma_f32_16x16x32_f16(af1[tt], b1, acc, 0, 0, 0);
                const int ocl = g2 * 16 + l15;
                const int prow = tile16 >> 1;
                const int blk  = ((tile16 & 1) << 1) | (quad >> 1);
                *(f32x4*)&shm.csh[ocl * 264 + prow * 32 + pcolrot(blk, prow, ocl)
                                  + (quad & 1) * 4] = acc;
            }
        }
        __syncthreads();

        // ---- R1 (rows) ----
#pragma unroll
        for (int di = 0; di < 4; ++di) {
            const int ocl = ch + 8 * di;
            float* row = &shm.csh[ocl * 264 + lan * 32 + pcolrot(pat, lan, ocl)];
            float v[8], o[8];
            *(f32x4*)&v[0] = *(const f32x4*)row;
            *(f32x4*)&v[4] = *(const f32x4*)(row + 4);
#pragma unroll
            for (int j = 0; j < 8; ++j) {
                float s = v[0] * MD[j][0];
#pragma unroll
                for (int q = 1; q < 8; ++q) s = fmaf(v[q], MD[j][q], s);
                o[j] = s;
            }
            *(f32x4*)row       = *(const f32x4*)&o[0];
            *(f32x4*)(row + 4) = *(const f32x4*)&o[4];
        }
        __syncthreads();

        // ---- Cols: d = M v ; d *= quant ; e = M^T d ----
#pragma unroll
        for (int di = 0; di < 4; ++di) {
            const int ocl = ch + 8 * di;
            float v[8], d[8], e[8];
#pragma unroll
            for (int i = 0; i < 8; ++i)
                v[i] = shm.csh[ocl * 264 + i * 32 + pcolrot(pat, i, ocl) + lan];
            int ocq = oc0 + ocl; if (ocq > C2 - 1) ocq = C2 - 1;
            const float* qp = quant + ocq * 64 + lan;
#pragma unroll
            for (int i = 0; i < 8; ++i) {
                float s = v[0] * MD[i][0];
#pragma unroll
                for (int p = 1; p < 8; ++p) s = fmaf(v[p], MD[i][p], s);
                d[i] = s * qp[i * 8];
            }
#pragma unroll
            for (int p = 0; p < 8; ++p) {
                float s = d[0] * MD[0][p];
#pragma unroll
                for (int i = 1; i < 8; ++i) s = fmaf(d[i], MD[i][p], s);
                e[p] = s;
            }
#pragma unroll
            for (int i = 0; i < 8; ++i)
                shm.csh[ocl * 264 + i * 32 + pcolrot(pat, i, ocl) + lan] = e[i];
        }
        __syncthreads();

        // ---- R2 (rows) -> global fp16, 64B full sectors ----
#pragma unroll
        for (int di = 0; di < 4; ++di) {
            const int ocl = ch + 8 * di;
            const int oc  = oc0 + ocl;
            const float* row = &shm.csh[ocl * 264 + lan * 32 + pcolrot(pat, lan, ocl)];
            float v[8];
            *(f32x4*)&v[0] = *(const f32x4*)row;
            *(f32x4*)&v[4] = *(const f32x4*)(row + 4);
            union { _Float16 h[8]; f16x8 f; } u;
#pragma unroll
            for (int q = 0; q < 8; ++q) {
                float s = v[0] * MD[0][q];
#pragma unroll
                for (int j = 1; j < 8; ++j) s = fmaf(v[j], MD[j][q], s);
                u.h[q] = (_Float16)s;
            }
            if (oc < C2) {
                f16x8* dst = (f16x8*)(yr + (size_t)(bb * C2 + oc) * NP
                                      + (y0 + lan) * HW + x0 + pat * 8);
                *dst = u.f;
            }
        }
        __syncthreads();
    }
}

// ---------------------------------------------------------------------------
// Kernel B: depthwise 3x3 + exact gelu gate (VALU) + project_out (MFMA).
// Block 256 = ONE image row (256x1 tile): no x-halo sector over-fetch,
// 1KB-contiguous out stores.  XCD strip swizzle: each XCD owns 32 contiguous
// rows so the vertical halo is L2-hot.  Epilogue FULLY unrolled: acc is
// statically indexed (round-4/5's `unroll 1` made acc dynamic -> scratch
// -> ~455 MB of spurious HBM writes).
// ---------------------------------------------------------------------------
__global__ __launch_bounds__(256, 2) void kB(
    const _Float16* __restrict__ yr,      // [nb][340][NP] fp16
    const float* __restrict__ Wdw,        // [340][9]
    const _Float16* __restrict__ WoutKH,  // [64][192] fp16 (zero-padded)
    float* __restrict__ out)              // [nb][64][256][256]
{
    const int tid = threadIdx.x;
    const int bb  = blockIdx.y;
    const int id  = blockIdx.x;                         // 0..255
    const int row = ((id & 7) << 5) | (id >> 3);        // XCD strip swizzle
    const int c   = tid;                                // column 0..255
    const int wv = tid >> 6;
    const int l15 = tid & 15, quad = (tid & 63) >> 4;

    __shared__ union {
        _Float16 g[256 * 32];    // 16384 B: g tile for one 32-h chunk
        float    t[16 * 257];    // 16448 B: epilogue transpose
    } shm;

    const _Float16* ybase = yr + (size_t)bb * C2 * NP;

    // 9 tap offsets (absolute within a channel plane); OOB -> zeroed pad.
    int off[9];
    {
        const int padoff = NPIX + (c & 63);
        int k = 0;
#pragma unroll
        for (int dy = -1; dy <= 1; ++dy)
#pragma unroll
            for (int dx = -1; dx <= 1; ++dx, ++k) {
                const int gy = row + dy, gx = c + dx;
                const bool ok = ((unsigned)gy < (unsigned)HW) && ((unsigned)gx < (unsigned)HW);
                off[k] = ok ? (gy * HW + gx) : padoff;
            }
    }

    f32x4 acc[4][4];   // [px-tile tt][oc-group p]
#pragma unroll
    for (int a = 0; a < 4; ++a)
#pragma unroll
        for (int b = 0; b < 4; ++b) acc[a][b] = (f32x4){0.f, 0.f, 0.f, 0.f};

#pragma unroll 1
    for (int chunk = 0; chunk < 6; ++chunk) {
        const int h0 = chunk * 32;

        // ---- g for 32 channels -> LDS fp16 (full unroll: max MLP) ----
#pragma unroll
        for (int u = 0; u < 4; ++u) {
            union { _Float16 h[8]; f16x8 v; } pk;
#pragma unroll
            for (int j = 0; j < 8; ++j) {
                const int h = h0 + u * 8 + j;
                float gg = 0.f;
                if (h < HID) {
                    const _Float16* p1 = ybase + (size_t)h * NP;
                    const _Float16* p2 = p1 + (size_t)HID * NP;
                    const float* w1 = Wdw + h * 9;
                    const float* w2 = w1 + HID * 9;
                    float s1 = 0.f, s2 = 0.f;
#pragma unroll
                    for (int k = 0; k < 9; ++k) {
                        s1 = fmaf((float)p1[off[k]], w1[k], s1);
                        s2 = fmaf((float)p2[off[k]], w2[k], s2);
                    }
                    gg = 0.5f * s1 * (1.f + erff(s1 * 0.70710678118654752f)) * s2;
                }
                pk.h[j] = (_Float16)gg;
            }
            *(f16x8*)&shm.g[tid * 32 + ((u ^ (tid & 3)) * 8)] = pk.v;
        }
        __syncthreads();

        // ---- MFMA: acc[px, oc] += g[px, h32] * WoutKH[oc][h32] ----
#pragma unroll
        for (int tt = 0; tt < 4; ++tt) {
            const int apx = (wv * 4 + tt) * 16 + l15;
            const f16x8 a = *(const f16x8*)&shm.g[apx * 32 + ((quad ^ (apx & 3)) * 8)];
#pragma unroll
            for (int p = 0; p < 4; ++p) {
                const f16x8 b = *(const f16x8*)(WoutKH + (p * 16 + l15) * 192 + h0 + quad * 8);
                acc[tt][p] = __builtin_amdgcn_mfma_f32_16x16x32_f16(a, b, acc[tt][p], 0, 0, 0);
            }
        }
        __syncthreads();
    }

    // ---- Epilogue: LDS transpose -> coalesced stores.  FULLY unrolled so
    //      acc indexing stays static (never scratch). ----
    float* ob = out + (size_t)bb * CIN * NPIX + row * HW + c;
#pragma unroll
    for (int p = 0; p < 4; ++p) {
#pragma unroll
        for (int tt = 0; tt < 4; ++tt) {
            const int px = (wv * 4 + tt) * 16 + quad * 4;
#pragma unroll
            for (int reg = 0; reg < 4; ++reg)
                shm.t[l15 * 257 + px + reg] = acc[tt][p][reg];
        }
        __syncthreads();
#pragma unroll
        for (int o2 = 0; o2 < 16; ++o2)
            ob[(size_t)(p * 16 + o2) * NPIX] = shm.t[o2 * 257 + tid];
        __syncthreads();
    }
}

extern "C" void kernel_launch(void* const* d_in, const int* in_sizes, int n_in,
                              void* d_out, int out_size, void* d_ws, size_t ws_size,
                              hipStream_t stream)
{
    const float* x     = (const float*)d_in[0];
    const float* Win   = (const float*)d_in[1];
    const float* Wdw   = (const float*)d_in[2];
    const float* quant = (const float*)d_in[3];
    const float* Wout  = (const float*)d_in[4];
    float* out = (float*)d_out;

    // ws: WinH [0,45056) ; WoutKH [45056,69632) ; yr at 69632 (16B aligned).
    _Float16* WinH   = (_Float16*)d_ws;
    _Float16* WoutKH = (_Float16*)((char*)d_ws + 45056);
    _Float16* yrbuf  = (_Float16*)((char*)d_ws + 69632);

    const size_t perBatch = (size_t)C2 * NP * sizeof(_Float16);  // 44.6 MB
    const size_t head = 69632;
    const size_t avail = ws_size > head ? ws_size - head : 0;
    int nb = 1;
    if (avail >= 4 * perBatch)      nb = 4;
    else if (avail >= 2 * perBatch) nb = 2;

    kprep<<<88, 256, 0, stream>>>(Win, Wout, WinH, WoutKH);

    for (int b0 = 0; b0 < 4; b0 += nb) {
        dim3 grid(256, nb);
        kA<<<grid, 256, 0, stream>>>(x + (size_t)b0 * CIN * NPIX, WinH, quant, yrbuf);
        kB<<<grid, 256, 0, stream>>>(yrbuf, Wdw, WoutKH, out + (size_t)b0 * CIN * NPIX);
    }
}